// Round 12
// baseline (524.005 us; speedup 1.0000x reference)
//
#include <hip/hip_runtime.h>
#include <cmath>

#define BATCH 64
#define SEQL  32
#define EMBD  300
#define HIDD  500
#define NOBJ  64
#define GHID  100
#define ANSN  1000

// partition: 4 batch-groups x 25 unit-blocks
#define GRP    4
#define GBATCH 16
#define BPG    25
#define UPB8   20
#define NBLK   (GRP*BPG)   // 100
#define SLOTP  32          // slot padding in ints (128 B)
#define KPX    328         // xg-phase LDS f16 row stride (656 B -> 2-way banks, free)

typedef _Float16 half8 __attribute__((ext_vector_type(8)));
typedef float    f32x4 __attribute__((ext_vector_type(4)));

__device__ __forceinline__ float sigmf(float x){ return 1.f/(1.f+expf(-x)); }

// sc1 (coherence-point) primitives: RELAXED agent-scope atomics, no cache-wide fences
__device__ __forceinline__ float2 ld_cc2(const unsigned long long* p){
    union { unsigned long long u; float2 f; } c;
    c.u = __hip_atomic_load(p, __ATOMIC_RELAXED, __HIP_MEMORY_SCOPE_AGENT);
    return c.f;
}
__device__ __forceinline__ void st_cc8(_Float16* p, unsigned long long v){
    __hip_atomic_store((unsigned long long*)p, v, __ATOMIC_RELAXED, __HIP_MEMORY_SCOPE_AGENT);
}
__device__ __forceinline__ void st_cc4(float* p, float v){
    __hip_atomic_store(p, v, __ATOMIC_RELAXED, __HIP_MEMORY_SCOPE_AGENT);
}

// group-local all-to-all barrier (one hop, fence-free; proven r8-r11)
__device__ __forceinline__ void gbarA(int* slots, int grp, int ub, int seq)
{
    __syncthreads();
    if (threadIdx.x == 0)
        __hip_atomic_store(slots + (grp*BPG + ub)*SLOTP, seq,
                           __ATOMIC_RELAXED, __HIP_MEMORY_SCOPE_AGENT);
    if (threadIdx.x < BPG){
        int* s = slots + (grp*BPG + threadIdx.x)*SLOTP;
        while (__hip_atomic_load(s, __ATOMIC_RELAXED, __HIP_MEMORY_SCOPE_AGENT) < seq)
            __builtin_amdgcn_s_sleep(1);
    }
    asm volatile("" ::: "memory");
    __syncthreads();
}

// ---------------- fused: xg GEMM + LSTM + tail, one cooperative dispatch ----------------
__global__ __launch_bounds__(320, 1) void k_fused(
    const int* __restrict__ sent, const float* __restrict__ table,
    const float* __restrict__ Wih, const float* __restrict__ b_ih, const float* __restrict__ b_hh,
    _Float16* __restrict__ hF, float* __restrict__ hqB, float* __restrict__ xgP,
    const float* __restrict__ Whh, const float* __restrict__ h0, const float* __restrict__ c0,
    const int* __restrict__ lens, int* __restrict__ slots,
    const float* __restrict__ conv, const float* __restrict__ g1w, const float* __restrict__ g1b,
    const float* __restrict__ g2w, const float* __restrict__ g2b,
    const float* __restrict__ f1w, const float* __restrict__ f1b,
    const float* __restrict__ f2w, const float* __restrict__ f2b,
    float* __restrict__ out)
{
    __shared__ __align__(16) char smem[133952];

    int tid = threadIdx.x, bid = blockIdx.x;
    int grp = bid / BPG, ub = bid - grp*BPG;
    int u0  = ub * UPB8;
    int w   = tid >> 6, lane = tid & 63;
    int rA  = lane & 15, kb = lane >> 4;

    // pointwise identity: 320 threads = 20 units x 16 batch
    int pb  = tid & 15, puu = tid >> 4;        // puu 0..19
    int pu  = u0 + puu;
    int gb  = grp*GBATCH + pb;
    float cprev = c0[gb*HIDD + pu];
    float hprev = h0[gb*HIDD + pu];
    int   mylen = lens[gb];
    float biasP[4];
    #pragma unroll
    for (int g = 0; g < 4; ++g) biasP[g] = b_ih[g*HIDD + pu] + b_hh[g*HIDD + pu];

    float* xgp = xgP + (size_t)bid * (80*512);   // private xg slice [80 rows][512 (t,b) cols]

    // ======== phase 1: private xg GEMM (own 80 gate-rows x group's 512 cols) ========
    {
        _Float16* WA = (_Float16*)smem;                 // [80][KPX]
        _Float16* SB = (_Float16*)(smem + 81920);       // [32][KPX]
        int* sidxL   = (int*)(smem + 102912);           // [512], m = t*16+bl
        for (int i = tid; i < 512; i += 320){
            int t = i >> 4, bl = i & 15;
            sidxL[i] = sent[(grp*GBATCH + bl)*SEQL + t];
        }
        for (int i = tid; i < 80*75; i += 320){
            int rl = i / 75, c4 = i - rl*75;
            int n = (rl/UPB8)*HIDD + u0 + (rl - (rl/UPB8)*UPB8);
            float4 v = *(const float4*)(Wih + (size_t)n*EMBD + c4*4);
            _Float16* d = WA + rl*KPX + c4*4;
            d[0]=(_Float16)v.x; d[1]=(_Float16)v.y; d[2]=(_Float16)v.z; d[3]=(_Float16)v.w;
        }
        for (int i = tid; i < 80*20; i += 320){
            int rl = i / 20;
            WA[rl*KPX + 300 + (i - rl*20)] = (_Float16)0.f;
        }
        __syncthreads();
        for (int ch = 0; ch < 16; ++ch){
            for (int i = tid; i < 32*75; i += 320){
                int ml = i / 75, c4 = i - ml*75;
                float4 v = *(const float4*)(table + (size_t)sidxL[ch*32+ml]*EMBD + c4*4);
                _Float16* d = SB + ml*KPX + c4*4;
                d[0]=(_Float16)v.x; d[1]=(_Float16)v.y; d[2]=(_Float16)v.z; d[3]=(_Float16)v.w;
            }
            for (int i = tid; i < 32*20; i += 320){
                int ml = i / 20;
                SB[ml*KPX + 300 + (i - ml*20)] = (_Float16)0.f;
            }
            __syncthreads();
            if (w < 4){
                for (int j = w; j < 10; j += 4){     // jobs: rt = j>>1 (5 row-tiles), mc = j&1
                    int rt = j >> 1, mc = j & 1;
                    f32x4 acc = {0.f,0.f,0.f,0.f};
                    #pragma unroll
                    for (int ks = 0; ks < 10; ++ks){
                        half8 af = *(const half8*)&WA[(rt*16 + rA)*KPX + ks*32 + kb*8];
                        half8 bf = *(const half8*)&SB[(mc*16 + rA)*KPX + ks*32 + kb*8];
                        acc = __builtin_amdgcn_mfma_f32_16x16x32_f16(af, bf, acc, 0, 0, 0);
                    }
                    #pragma unroll
                    for (int r = 0; r < 4; ++r)
                        xgp[(size_t)(rt*16 + kb*4 + r)*512 + ch*32 + mc*16 + rA] = acc[r];
                }
            }
            __syncthreads();
        }
    }

    // ======== phase 2: Whh -> Wl (swizzled), h(-1) init, pads, group barrier ========
    _Float16* Wl  = (_Float16*)smem;                 // [80*512], swizzled
    _Float16* hls = (_Float16*)(smem + 81920);       // [16*512], swizzled
    float*    gl  = (float*)(smem + 98304);          // [4*80*16]
    _Float16* hout= (_Float16*)(smem + 118784);      // [16*UPB8]

    for (int i = tid; i < 80*512; i += 320){
        int m = i >> 9, k = i & 511;
        int g = m / UPB8, uu = m - g*UPB8;
        float v = (k < HIDD) ? Whh[(size_t)(g*HIDD + u0 + uu)*HIDD + k] : 0.f;
        int off = (i*2) ^ ((m & 7) << 4);
        *(_Float16*)((char*)Wl + off) = (_Float16)v;
    }
    hout[pb*UPB8 + puu] = (_Float16)hprev;
    __syncthreads();
    if (tid < 80){
        int b = tid / 5, q = tid - (tid/5)*5;
        unsigned long long v = *(const unsigned long long*)((const char*)hout + b*40 + q*8);
        st_cc8(hF + ((size_t)(1*GRP + grp)*GBATCH + b)*512 + u0 + q*4, v);
    }
    if (ub == 0 && tid >= 128 && tid < 224){   // zero k-pad 500..511, both buffers
        int j = tid - 128;
        int buf = j / 48, r = j - buf*48;
        int b = r / 3, q = r - (r/3)*3;
        st_cc8(hF + ((size_t)(buf*GRP + grp)*GBATCH + b)*512 + 500 + q*4, 0ULL);
    }
    gbarA(slots, grp, ub, 1);

    // ======== phase 3: LSTM t-loop (r11 verbatim; xg read from private slice) ========
    for (int t = 0; t < SEQL; ++t){
        {
            const char* src = (const char*)(hF + (size_t)(((t&1)^1)*GRP + grp)*GBATCH*512);
            for (int idx = tid; idx < 2048; idx += 320){
                int o = idx*8;
                float2 v = ld_cc2((const unsigned long long*)(src + o));
                *(float2*)((char*)hls + (o ^ (((o >> 10) & 7) << 4))) = v;
            }
        }
        __syncthreads();

        if (w < 4){
            f32x4 acc[5] = {};
            half8 bf[4];
            #pragma unroll
            for (int ks4 = 0; ks4 < 4; ++ks4){
                int kByte = (w*4 + ks4)*64 + kb*16;
                int bOff  = (rA*1024 + kByte) ^ ((rA & 7) << 4);
                bf[ks4] = *(const half8*)((const char*)hls + bOff);
            }
            #pragma unroll
            for (int rt = 0; rt < 5; ++rt){
                #pragma unroll
                for (int ks4 = 0; ks4 < 4; ++ks4){
                    int kByte = (w*4 + ks4)*64 + kb*16;
                    int m = rt*16 + rA;
                    int aOff = (m*1024 + kByte) ^ ((m & 7) << 4);
                    half8 af = *(const half8*)((const char*)Wl + aOff);
                    acc[rt] = __builtin_amdgcn_mfma_f32_16x16x32_f16(af, bf[ks4], acc[rt], 0, 0, 0);
                }
            }
            #pragma unroll
            for (int rt = 0; rt < 5; ++rt)
                #pragma unroll
                for (int r = 0; r < 4; ++r)
                    gl[(w*80 + rt*16 + kb*4 + r)*16 + rA] = acc[rt][r];
        }
        __syncthreads();

        {
            float g4[4];
            #pragma unroll
            for (int g = 0; g < 4; ++g){
                int row = g*UPB8 + puu;
                float s = gl[(0*80 + row)*16 + pb] + gl[(1*80 + row)*16 + pb]
                        + gl[(2*80 + row)*16 + pb] + gl[(3*80 + row)*16 + pb];
                s += xgp[(size_t)row*512 + t*16 + pb] + biasP[g];
                g4[g] = s;
            }
            float si = sigmf(g4[0]), sf = sigmf(g4[1]);
            float tg = tanhf(g4[2]), so = sigmf(g4[3]);
            float cn = sf*cprev + si*tg;
            float hn = so*tanhf(cn);
            if (t < mylen){ cprev = cn; hprev = hn; }
            hout[pb*UPB8 + puu] = (_Float16)hprev;
            if (t == SEQL-1) st_cc4(hqB + (size_t)gb*512 + pu, hprev);
        }
        if (t < SEQL-1){
            __syncthreads();
            if (tid < 80){
                int b = tid / 5, q = tid - (tid/5)*5;
                unsigned long long v = *(const unsigned long long*)((const char*)hout + b*40 + q*8);
                st_cc8(hF + ((size_t)((t&1)*GRP + grp)*GBATCH + b)*512 + u0 + q*4, v);
            }
            gbarA(slots, grp, ub, t + 2);
        }
    }

    // ======== phase 4: global barrier over all 100 blocks ========
    __syncthreads();   // drains vmcnt -> hqB sc1 stores acked
    if (tid == 0)
        __hip_atomic_store(slots + bid*SLOTP, SEQL + 1,
                           __ATOMIC_RELAXED, __HIP_MEMORY_SCOPE_AGENT);
    if (bid >= BATCH) return;          // producers done
    if (tid < NBLK){
        int* s = slots + tid*SLOTP;
        while (__hip_atomic_load(s, __ATOMIC_RELAXED, __HIP_MEMORY_SCOPE_AGENT) < SEQL + 1)
            __builtin_amdgcn_s_sleep(1);
    }
    asm volatile("" ::: "memory");
    __syncthreads();

    // ======== phase 5: tail (b = bid): qp/ipjp + pair MFMA + f1/f2 + log_softmax ========
    {
        int b = bid;
        float*    convl = (float*)smem;                 // [24*64]
        float*    g1ij  = (float*)(smem + 6144);        // [100][48]
        float*    hb    = (float*)(smem + 25344);       // [512]
        float*    qpl   = (float*)(smem + 27392);       // [112]
        float*    ipl   = (float*)(smem + 27840);       // [64][104]
        float*    jpl   = (float*)(smem + 54464);       // [64][132]
        float*    basel = (float*)(smem + 88256);       // [16][132]
        _Float16* g2h   = (_Float16*)(smem + 96704);    // [112][136]
        float*    redx  = (float*)(smem + 127168);      // [4][112]
        float*    gs    = (float*)(smem + 128960);      // [112]
        float*    fh    = (float*)(smem + 129408);      // [112]
        float*    lg    = (float*)(smem + 129856);      // [1000]
        float*    redm  = (float*)(smem + 133856);      // [8]
        float*    red2  = (float*)(smem + 133888);      // [8]

        for (int i = tid; i < 24*64; i += 320)
            convl[i] = conv[(size_t)b*24*64 + i];
        for (int i = tid; i < 100*48; i += 320){
            int n = i/48, c = i - n*48;
            g1ij[n*48 + c] = g1w[(size_t)n*548 + 500 + c];
        }
        if (tid < 256){
            float2 v = ld_cc2((const unsigned long long*)(hqB + (size_t)b*512) + tid);
            hb[tid*2] = v.x; hb[tid*2+1] = v.y;
        }
        for (int i = tid; i < 112*136; i += 320){
            int n = i/136, k = i - n*136;
            g2h[n*136 + k] = (n < 100 && k < 100) ? (_Float16)g2w[n*GHID + k] : (_Float16)0.f;
        }
        __syncthreads();

        if (tid < 100){
            const float4* wr = (const float4*)(g1w + (size_t)tid*548);
            float s = g1b[tid];
            #pragma unroll 5
            for (int k4 = 0; k4 < 125; ++k4){
                float4 v = wr[k4];
                s += v.x*hb[k4*4] + v.y*hb[k4*4+1] + v.z*hb[k4*4+2] + v.w*hb[k4*4+3];
            }
            qpl[tid] = s;
        }
        for (int i = tid; i < NOBJ*100; i += 320){
            int o = i / 100, n = i - (i/100)*100;
            float sj = 0.f, si = 0.f;
            #pragma unroll
            for (int c = 0; c < 24; ++c){
                float v = convl[c*64 + o];
                sj += v * g1ij[n*48 + c];
                si += v * g1ij[n*48 + 24 + c];
            }
            ipl[o*104 + n] = si;
            jpl[o*132 + n] = sj;
        }
        for (int i = tid; i < NOBJ*32; i += 320) jpl[(i>>5)*132 + 100 + (i&31)] = 0.f;

        float gb7[7];
        #pragma unroll
        for (int nt = 0; nt < 7; ++nt){
            int n = nt*16 + rA;
            gb7[nt] = (n < 100) ? g2b[n] : 0.f;
        }

        f32x4 sacc[7] = {};
        for (int ic = 0; ic < 4; ++ic){
            __syncthreads();
            for (int i = tid; i < 16*132; i += 320){
                int il = i / 132, k = i - il*132;
                basel[il*132 + k] = (k < 100) ? qpl[k] + ipl[(ic*16 + il)*104 + k] : 0.f;
            }
            __syncthreads();
            if (w < 4){
                #pragma unroll
                for (int it = 0; it < 4; ++it){
                    int il = w*4 + it;
                    #pragma unroll
                    for (int jc = 0; jc < 4; ++jc){
                        f32x4 acc[7] = {};
                        int jrow = jc*16 + rA;
                        #pragma unroll
                        for (int ks = 0; ks < 4; ++ks){
                            int k0 = ks*32 + kb*8;
                            const float* jpp = &jpl[jrow*132 + k0];
                            const float* bpp = &basel[il*132 + k0];
                            half8 af;
                            #pragma unroll
                            for (int e = 0; e < 8; ++e)
                                af[e] = (_Float16)fmaxf(jpp[e] + bpp[e], 0.f);
                            #pragma unroll
                            for (int nt = 0; nt < 7; ++nt){
                                half8 bf = *(const half8*)&g2h[(nt*16 + rA)*136 + k0];
                                acc[nt] = __builtin_amdgcn_mfma_f32_16x16x32_f16(af, bf, acc[nt], 0, 0, 0);
                            }
                        }
                        #pragma unroll
                        for (int nt = 0; nt < 7; ++nt)
                            #pragma unroll
                            for (int r = 0; r < 4; ++r)
                                sacc[nt][r] += fmaxf(acc[nt][r] + gb7[nt], 0.f);
                    }
                }
            }
        }
        if (w < 4){
            #pragma unroll
            for (int nt = 0; nt < 7; ++nt){
                float s = sacc[nt][0] + sacc[nt][1] + sacc[nt][2] + sacc[nt][3];
                s += __shfl_xor(s, 16);
                s += __shfl_xor(s, 32);
                if (lane < 16) redx[w*112 + nt*16 + lane] = s;
            }
        }
        __syncthreads();
        if (tid < 100)
            gs[tid] = redx[0*112+tid] + redx[1*112+tid] + redx[2*112+tid] + redx[3*112+tid];
        __syncthreads();

        if (tid < 100){
            const float4* wr = (const float4*)(f1w + (size_t)tid*GHID);
            float s = f1b[tid];
            #pragma unroll 5
            for (int k4 = 0; k4 < 25; ++k4){
                float4 v = wr[k4];
                s += v.x*gs[k4*4] + v.y*gs[k4*4+1] + v.z*gs[k4*4+2] + v.w*gs[k4*4+3];
            }
            fh[tid] = fmaxf(s, 0.f);
        }
        __syncthreads();

        for (int n = tid; n < ANSN; n += 320){
            const float4* wr = (const float4*)(f2w + (size_t)n*GHID);
            float s = f2b[n];
            #pragma unroll 5
            for (int k4 = 0; k4 < 25; ++k4){
                float4 v = wr[k4];
                s += v.x*fh[k4*4] + v.y*fh[k4*4+1] + v.z*fh[k4*4+2] + v.w*fh[k4*4+3];
            }
            lg[n] = fmaxf(s, 0.f);
        }
        __syncthreads();
        float mx = -1e30f;
        for (int n = tid; n < ANSN; n += 320) mx = fmaxf(mx, lg[n]);
        #pragma unroll
        for (int off = 32; off > 0; off >>= 1) mx = fmaxf(mx, __shfl_xor(mx, off));
        if (lane == 0) redm[w] = mx;
        __syncthreads();
        mx = fmaxf(fmaxf(fmaxf(redm[0], redm[1]), fmaxf(redm[2], redm[3])), redm[4]);
        float se = 0.f;
        for (int n = tid; n < ANSN; n += 320) se += expf(lg[n]-mx);
        #pragma unroll
        for (int off = 32; off > 0; off >>= 1) se += __shfl_xor(se, off);
        if (lane == 0) red2[w] = se;
        __syncthreads();
        se = red2[0] + red2[1] + red2[2] + red2[3] + red2[4];
        float lse = logf(se);
        for (int n = tid; n < ANSN; n += 320)
            out[(size_t)b*ANSN + n] = lg[n] - mx - lse;
    }
}

extern "C" void kernel_launch(void* const* d_in, const int* in_sizes, int n_in,
                              void* d_out, int out_size, void* d_ws, size_t ws_size,
                              hipStream_t stream)
{
    const int*   sent  = (const int*)  d_in[0];
    const float* conv  = (const float*)d_in[1];
    const int*   lens  = (const int*)  d_in[2];
    const float* table = (const float*)d_in[3];
    const float* W_ih  = (const float*)d_in[4];
    const float* W_hh  = (const float*)d_in[5];
    const float* b_ih  = (const float*)d_in[6];
    const float* b_hh  = (const float*)d_in[7];
    const float* h0    = (const float*)d_in[8];
    const float* c0    = (const float*)d_in[9];
    const float* g1_w  = (const float*)d_in[10];
    const float* g1_b  = (const float*)d_in[11];
    const float* g2_w  = (const float*)d_in[12];
    const float* g2_b  = (const float*)d_in[13];
    const float* f1_w  = (const float*)d_in[14];
    const float* f1_b  = (const float*)d_in[15];
    const float* f2_w  = (const float*)d_in[16];
    const float* f2_b  = (const float*)d_in[17];
    float* out = (float*)d_out;

    float* ws   = (float*)d_ws;
    int*   slots= (int*)d_ws;                          // 100 slots * 32 ints (64 KB region)
    _Float16* hF = (_Float16*)(ws + 16384);            // 2*4*16*512 f16 = 128 KB
    float* hqB  = ws + 16384 + 32768;                  // 64*512 f32
    float* xgP  = hqB + 64*512;                        // 100 * 80*512 f32 = 16.4 MB

    // 0. zero barrier region (deterministic across graph replays)
    hipMemsetAsync(slots, 0, 16384*sizeof(float), stream);

    // 1. everything else: one cooperative kernel
    {
        const int* sent_p = sent; const float* table_p = table;
        const float* Wih_p = W_ih; const float* bih_p = b_ih; const float* bhh_p = b_hh;
        _Float16* hF_p = hF; float* hqB_p = hqB; float* xgP_p = xgP;
        const float* Whh_p = W_hh; const float* h0_p = h0; const float* c0_p = c0;
        const int* lens_p = lens; int* slots_p = slots;
        const float* conv_p = conv;
        const float* g1w_p = g1_w; const float* g1b_p = g1_b;
        const float* g2w_p = g2_w; const float* g2b_p = g2_b;
        const float* f1w_p = f1_w; const float* f1b_p = f1_b;
        const float* f2w_p = f2_w; const float* f2b_p = f2_b;
        float* out_p = out;
        void* kargs[] = {
            (void*)&sent_p, (void*)&table_p, (void*)&Wih_p, (void*)&bih_p, (void*)&bhh_p,
            (void*)&hF_p, (void*)&hqB_p, (void*)&xgP_p,
            (void*)&Whh_p, (void*)&h0_p, (void*)&c0_p, (void*)&lens_p, (void*)&slots_p,
            (void*)&conv_p, (void*)&g1w_p, (void*)&g1b_p,
            (void*)&g2w_p, (void*)&g2b_p, (void*)&f1w_p, (void*)&f1b_p,
            (void*)&f2w_p, (void*)&f2b_p, (void*)&out_p };
        hipLaunchCooperativeKernel((const void*)k_fused, dim3(NBLK), dim3(320),
                                   kargs, 0, stream);
    }
}

// Round 13
// 476.215 us; speedup vs baseline: 1.1004x; 1.1004x over previous
//
#include <hip/hip_runtime.h>
#include <cmath>

#define BATCH 64
#define SEQL  32
#define EMBD  300
#define HIDD  500
#define NOBJ  64
#define GHID  100
#define ANSN  1000
#define MCOL  2048   // t*64+b column dimension

// partition: 4 batch-groups x 25 unit-blocks
#define GRP    4
#define GBATCH 16
#define BPG    25
#define UPB8   20
#define NBLK   (GRP*BPG)   // 100
#define SLOTP  32          // slot padding in ints (128 B)

#define KPADX  328         // xg LDS row stride in f16 (656 B)
#define TCH    4           // timesteps per xg block

typedef _Float16 half8 __attribute__((ext_vector_type(8)));
typedef float    f32x4 __attribute__((ext_vector_type(4)));

__device__ __forceinline__ float sigmf(float x){ return 1.f/(1.f+expf(-x)); }

// sc1 (coherence-point) primitives: RELAXED agent-scope atomics, no cache-wide fences
__device__ __forceinline__ float2 ld_cc2(const unsigned long long* p){
    union { unsigned long long u; float2 f; } c;
    c.u = __hip_atomic_load(p, __ATOMIC_RELAXED, __HIP_MEMORY_SCOPE_AGENT);
    return c.f;
}
__device__ __forceinline__ void st_cc8(_Float16* p, unsigned long long v){
    __hip_atomic_store((unsigned long long*)p, v, __ATOMIC_RELAXED, __HIP_MEMORY_SCOPE_AGENT);
}
__device__ __forceinline__ void st_cc4(float* p, float v){
    __hip_atomic_store(p, v, __ATOMIC_RELAXED, __HIP_MEMORY_SCOPE_AGENT);
}

// ---------------- k_xg2: xgT = W_ih @ emb + bias (MFMA f16, r11-proven) + slot zeroing ----------------
__global__ __launch_bounds__(256, 1) void k_xg2(
    const int* __restrict__ sent, const float* __restrict__ table,
    const float* __restrict__ Wih, const float* __restrict__ b_ih,
    const float* __restrict__ b_hh, float* __restrict__ xgT, int* __restrict__ slots)
{
    __shared__ _Float16 Sh[64*KPADX];   // 41984 B, A then B
    __shared__ int sidx[TCH][64];
    int tid = threadIdx.x;
    int tc = blockIdx.x;                // t-chunk (0..7)
    int n0 = blockIdx.y * 64;
    int w = tid >> 6, lane = tid & 63;
    int rA = lane & 15, kb = lane >> 4;

    // zero barrier slots for the following kernel (fresh every launch/replay)
    if (tc == 0 && blockIdx.y == 0 && tid < NBLK)
        __hip_atomic_store(slots + tid*SLOTP, 0, __ATOMIC_RELAXED, __HIP_MEMORY_SCOPE_AGENT);

    for (int i = tid; i < TCH*64; i += 256){
        int tt = i >> 6, b = i & 63;
        sidx[tt][b] = sent[b*SEQL + tc*TCH + tt];
    }
    // stage A: 64 rows x 75 float4 (k=300 exact), f32->f16
    for (int i = tid; i < 64*75; i += 256){
        int n = i / 75, c4 = i - (i/75)*75;
        float4 v = {0.f,0.f,0.f,0.f};
        if (n0 + n < 2000)
            v = *(const float4*)(Wih + (size_t)(n0+n)*300 + c4*4);
        _Float16* dst = &Sh[n*KPADX + c4*4];
        dst[0]=(_Float16)v.x; dst[1]=(_Float16)v.y; dst[2]=(_Float16)v.z; dst[3]=(_Float16)v.w;
    }
    for (int i = tid; i < 64*20; i += 256){   // zero pad k 300..319
        int n = i / 20, k = 300 + (i - (i/20)*20);
        Sh[n*KPADX + k] = (_Float16)0.f;
    }
    __syncthreads();
    // A-fragments -> registers (static indices)
    half8 areg[10];
    #pragma unroll
    for (int ks = 0; ks < 10; ++ks)
        areg[ks] = *(const half8*)&Sh[(w*16 + rA)*KPADX + ks*32 + kb*8];
    float biasr[4];
    #pragma unroll
    for (int r = 0; r < 4; ++r){
        int n = n0 + w*16 + kb*4 + r;
        biasr[r] = (n < 2000) ? b_ih[n] + b_hh[n] : 0.f;
    }
    __syncthreads();   // all A reads done before B overwrites Sh

    for (int tt = 0; tt < TCH; ++tt){
        for (int i = tid; i < 64*75; i += 256){
            int m = i / 75, c4 = i - (i/75)*75;
            float4 v = *(const float4*)(table + (size_t)sidx[tt][m]*300 + c4*4);
            _Float16* dst = &Sh[m*KPADX + c4*4];
            dst[0]=(_Float16)v.x; dst[1]=(_Float16)v.y; dst[2]=(_Float16)v.z; dst[3]=(_Float16)v.w;
        }
        for (int i = tid; i < 64*20; i += 256){
            int m = i / 20, k = 300 + (i - (i/20)*20);
            Sh[m*KPADX + k] = (_Float16)0.f;
        }
        __syncthreads();

        f32x4 acc[4] = {};
        #pragma unroll
        for (int ks = 0; ks < 10; ++ks){
            #pragma unroll
            for (int mc = 0; mc < 4; ++mc){
                half8 bf = *(const half8*)&Sh[(mc*16 + rA)*KPADX + ks*32 + kb*8];
                acc[mc] = __builtin_amdgcn_mfma_f32_16x16x32_f16(areg[ks], bf, acc[mc], 0, 0, 0);
            }
        }
        #pragma unroll
        for (int r = 0; r < 4; ++r){
            int n = n0 + w*16 + kb*4 + r;
            if (n < 2000){
                #pragma unroll
                for (int mc = 0; mc < 4; ++mc)
                    xgT[(size_t)n*MCOL + (tc*TCH+tt)*64 + mc*16 + rA] = acc[mc][r] + biasr[r];
            }
        }
        __syncthreads();
    }
}

// group-local all-to-all barrier (one hop, fence-free; proven r8-r12)
__device__ __forceinline__ void gbarA(int* slots, int grp, int ub, int seq)
{
    __syncthreads();
    if (threadIdx.x == 0)
        __hip_atomic_store(slots + (grp*BPG + ub)*SLOTP, seq,
                           __ATOMIC_RELAXED, __HIP_MEMORY_SCOPE_AGENT);
    if (threadIdx.x < BPG){
        int* s = slots + (grp*BPG + threadIdx.x)*SLOTP;
        while (__hip_atomic_load(s, __ATOMIC_RELAXED, __HIP_MEMORY_SCOPE_AGENT) < seq)
            __builtin_amdgcn_s_sleep(1);
    }
    asm volatile("" ::: "memory");
    __syncthreads();
}

// ---------------- k_lstm_tail: LSTM (r11 phase) + global barrier + tail (r12 phase), regular launch ----------------
__global__ __launch_bounds__(320, 1) void k_lstm_tail(
    _Float16* __restrict__ hF, float* __restrict__ hqB,
    const float* __restrict__ xgT, const float* __restrict__ Whh,
    const float* __restrict__ h0, const float* __restrict__ c0,
    const int* __restrict__ lens, int* __restrict__ slots,
    const float* __restrict__ conv, const float* __restrict__ g1w, const float* __restrict__ g1b,
    const float* __restrict__ g2w, const float* __restrict__ g2b,
    const float* __restrict__ f1w, const float* __restrict__ f1b,
    const float* __restrict__ f2w, const float* __restrict__ f2b,
    float* __restrict__ out)
{
    __shared__ __align__(16) char smem[133952];

    int tid = threadIdx.x, bid = blockIdx.x;
    int grp = bid / BPG, ub = bid - grp*BPG;
    int u0  = ub * UPB8;
    int w   = tid >> 6, lane = tid & 63;
    int rA  = lane & 15, kb = lane >> 4;

    int pb  = tid & 15, puu = tid >> 4;        // puu 0..19
    int pu  = u0 + puu;
    int gb  = grp*GBATCH + pb;
    float cprev = c0[gb*HIDD + pu];
    float hprev = h0[gb*HIDD + pu];
    int   mylen = lens[gb];

    // ======== phase 1: Whh -> Wl (swizzled), h(-1) init, pads, group barrier ========
    _Float16* Wl  = (_Float16*)smem;                 // [80*512], swizzled
    _Float16* hls = (_Float16*)(smem + 81920);       // [16*512], swizzled
    float*    gl  = (float*)(smem + 98304);          // [4*80*16]
    _Float16* hout= (_Float16*)(smem + 118784);      // [16*UPB8]

    for (int i = tid; i < 80*512; i += 320){
        int m = i >> 9, k = i & 511;
        int g = m / UPB8, uu = m - g*UPB8;
        float v = (k < HIDD) ? Whh[(size_t)(g*HIDD + u0 + uu)*HIDD + k] : 0.f;
        int off = (i*2) ^ ((m & 7) << 4);
        *(_Float16*)((char*)Wl + off) = (_Float16)v;
    }
    hout[pb*UPB8 + puu] = (_Float16)hprev;
    __syncthreads();
    if (tid < 80){
        int b = tid / 5, q = tid - (tid/5)*5;
        unsigned long long v = *(const unsigned long long*)((const char*)hout + b*40 + q*8);
        st_cc8(hF + ((size_t)(1*GRP + grp)*GBATCH + b)*512 + u0 + q*4, v);
    }
    if (ub == 0 && tid >= 128 && tid < 224){   // zero k-pad 500..511, both buffers
        int j = tid - 128;
        int buf = j / 48, r = j - buf*48;
        int b = r / 3, q = r - (r/3)*3;
        st_cc8(hF + ((size_t)(buf*GRP + grp)*GBATCH + b)*512 + 500 + q*4, 0ULL);
    }
    gbarA(slots, grp, ub, 1);

    // ======== phase 2: LSTM t-loop (r11 verbatim) ========
    for (int t = 0; t < SEQL; ++t){
        {
            const char* src = (const char*)(hF + (size_t)(((t&1)^1)*GRP + grp)*GBATCH*512);
            for (int idx = tid; idx < 2048; idx += 320){
                int o = idx*8;
                float2 v = ld_cc2((const unsigned long long*)(src + o));
                *(float2*)((char*)hls + (o ^ (((o >> 10) & 7) << 4))) = v;
            }
        }
        __syncthreads();

        if (w < 4){
            f32x4 acc[5] = {};
            half8 bf[4];
            #pragma unroll
            for (int ks4 = 0; ks4 < 4; ++ks4){
                int kByte = (w*4 + ks4)*64 + kb*16;
                int bOff  = (rA*1024 + kByte) ^ ((rA & 7) << 4);
                bf[ks4] = *(const half8*)((const char*)hls + bOff);
            }
            #pragma unroll
            for (int rt = 0; rt < 5; ++rt){
                #pragma unroll
                for (int ks4 = 0; ks4 < 4; ++ks4){
                    int kByte = (w*4 + ks4)*64 + kb*16;
                    int m = rt*16 + rA;
                    int aOff = (m*1024 + kByte) ^ ((m & 7) << 4);
                    half8 af = *(const half8*)((const char*)Wl + aOff);
                    acc[rt] = __builtin_amdgcn_mfma_f32_16x16x32_f16(af, bf[ks4], acc[rt], 0, 0, 0);
                }
            }
            #pragma unroll
            for (int rt = 0; rt < 5; ++rt)
                #pragma unroll
                for (int r = 0; r < 4; ++r)
                    gl[(w*80 + rt*16 + kb*4 + r)*16 + rA] = acc[rt][r];
        }
        __syncthreads();

        {
            float g4[4];
            #pragma unroll
            for (int g = 0; g < 4; ++g){
                int row = g*UPB8 + puu;
                float s = gl[(0*80 + row)*16 + pb] + gl[(1*80 + row)*16 + pb]
                        + gl[(2*80 + row)*16 + pb] + gl[(3*80 + row)*16 + pb];
                s += xgT[(size_t)(g*HIDD + pu)*MCOL + t*64 + gb];
                g4[g] = s;
            }
            float si = sigmf(g4[0]), sf = sigmf(g4[1]);
            float tg = tanhf(g4[2]), so = sigmf(g4[3]);
            float cn = sf*cprev + si*tg;
            float hn = so*tanhf(cn);
            if (t < mylen){ cprev = cn; hprev = hn; }
            hout[pb*UPB8 + puu] = (_Float16)hprev;
            if (t == SEQL-1) st_cc4(hqB + (size_t)gb*512 + pu, hprev);
        }
        if (t < SEQL-1){
            __syncthreads();
            if (tid < 80){
                int b = tid / 5, q = tid - (tid/5)*5;
                unsigned long long v = *(const unsigned long long*)((const char*)hout + b*40 + q*8);
                st_cc8(hF + ((size_t)((t&1)*GRP + grp)*GBATCH + b)*512 + u0 + q*4, v);
            }
            gbarA(slots, grp, ub, t + 2);
        }
    }

    // ======== phase 3: global barrier over all 100 blocks (r12-proven) ========
    __syncthreads();   // drains vmcnt -> hqB sc1 stores acked
    if (tid == 0)
        __hip_atomic_store(slots + bid*SLOTP, SEQL + 1,
                           __ATOMIC_RELAXED, __HIP_MEMORY_SCOPE_AGENT);
    if (bid >= BATCH) return;          // producers done
    if (tid < NBLK){
        int* s = slots + tid*SLOTP;
        while (__hip_atomic_load(s, __ATOMIC_RELAXED, __HIP_MEMORY_SCOPE_AGENT) < SEQL + 1)
            __builtin_amdgcn_s_sleep(1);
    }
    asm volatile("" ::: "memory");
    __syncthreads();

    // ======== phase 4: tail (b = bid): qp/ipjp + pair MFMA + f1/f2 + log_softmax (r12-proven) ========
    {
        int b = bid;
        float*    convl = (float*)smem;                 // [24*64]
        float*    g1ij  = (float*)(smem + 6144);        // [100][48]
        float*    hb    = (float*)(smem + 25344);       // [512]
        float*    qpl   = (float*)(smem + 27392);       // [112]
        float*    ipl   = (float*)(smem + 27840);       // [64][104]
        float*    jpl   = (float*)(smem + 54464);       // [64][132]
        float*    basel = (float*)(smem + 88256);       // [16][132]
        _Float16* g2h   = (_Float16*)(smem + 96704);    // [112][136]
        float*    redx  = (float*)(smem + 127168);      // [4][112]
        float*    gs    = (float*)(smem + 128960);      // [112]
        float*    fh    = (float*)(smem + 129408);      // [112]
        float*    lg    = (float*)(smem + 129856);      // [1000]
        float*    redm  = (float*)(smem + 133856);      // [8]
        float*    red2  = (float*)(smem + 133888);      // [8]

        for (int i = tid; i < 24*64; i += 320)
            convl[i] = conv[(size_t)b*24*64 + i];
        for (int i = tid; i < 100*48; i += 320){
            int n = i/48, c = i - n*48;
            g1ij[n*48 + c] = g1w[(size_t)n*548 + 500 + c];
        }
        if (tid < 256){
            float2 v = ld_cc2((const unsigned long long*)(hqB + (size_t)b*512) + tid);
            hb[tid*2] = v.x; hb[tid*2+1] = v.y;
        }
        for (int i = tid; i < 112*136; i += 320){
            int n = i/136, k = i - n*136;
            g2h[n*136 + k] = (n < 100 && k < 100) ? (_Float16)g2w[n*GHID + k] : (_Float16)0.f;
        }
        __syncthreads();

        if (tid < 100){
            const float4* wr = (const float4*)(g1w + (size_t)tid*548);
            float s = g1b[tid];
            #pragma unroll 5
            for (int k4 = 0; k4 < 125; ++k4){
                float4 v = wr[k4];
                s += v.x*hb[k4*4] + v.y*hb[k4*4+1] + v.z*hb[k4*4+2] + v.w*hb[k4*4+3];
            }
            qpl[tid] = s;
        }
        for (int i = tid; i < NOBJ*100; i += 320){
            int o = i / 100, n = i - (i/100)*100;
            float sj = 0.f, si = 0.f;
            #pragma unroll
            for (int c = 0; c < 24; ++c){
                float v = convl[c*64 + o];
                sj += v * g1ij[n*48 + c];
                si += v * g1ij[n*48 + 24 + c];
            }
            ipl[o*104 + n] = si;
            jpl[o*132 + n] = sj;
        }
        for (int i = tid; i < NOBJ*32; i += 320) jpl[(i>>5)*132 + 100 + (i&31)] = 0.f;

        float gb7[7];
        #pragma unroll
        for (int nt = 0; nt < 7; ++nt){
            int n = nt*16 + rA;
            gb7[nt] = (n < 100) ? g2b[n] : 0.f;
        }

        f32x4 sacc[7] = {};
        for (int ic = 0; ic < 4; ++ic){
            __syncthreads();
            for (int i = tid; i < 16*132; i += 320){
                int il = i / 132, k = i - il*132;
                basel[il*132 + k] = (k < 100) ? qpl[k] + ipl[(ic*16 + il)*104 + k] : 0.f;
            }
            __syncthreads();
            if (w < 4){
                #pragma unroll
                for (int it = 0; it < 4; ++it){
                    int il = w*4 + it;
                    #pragma unroll
                    for (int jc = 0; jc < 4; ++jc){
                        f32x4 acc[7] = {};
                        int jrow = jc*16 + rA;
                        #pragma unroll
                        for (int ks = 0; ks < 4; ++ks){
                            int k0 = ks*32 + kb*8;
                            const float* jpp = &jpl[jrow*132 + k0];
                            const float* bpp = &basel[il*132 + k0];
                            half8 af;
                            #pragma unroll
                            for (int e = 0; e < 8; ++e)
                                af[e] = (_Float16)fmaxf(jpp[e] + bpp[e], 0.f);
                            #pragma unroll
                            for (int nt = 0; nt < 7; ++nt){
                                half8 bf = *(const half8*)&g2h[(nt*16 + rA)*136 + k0];
                                acc[nt] = __builtin_amdgcn_mfma_f32_16x16x32_f16(af, bf, acc[nt], 0, 0, 0);
                            }
                        }
                        #pragma unroll
                        for (int nt = 0; nt < 7; ++nt)
                            #pragma unroll
                            for (int r = 0; r < 4; ++r)
                                sacc[nt][r] += fmaxf(acc[nt][r] + gb7[nt], 0.f);
                    }
                }
            }
        }
        if (w < 4){
            #pragma unroll
            for (int nt = 0; nt < 7; ++nt){
                float s = sacc[nt][0] + sacc[nt][1] + sacc[nt][2] + sacc[nt][3];
                s += __shfl_xor(s, 16);
                s += __shfl_xor(s, 32);
                if (lane < 16) redx[w*112 + nt*16 + lane] = s;
            }
        }
        __syncthreads();
        if (tid < 100)
            gs[tid] = redx[0*112+tid] + redx[1*112+tid] + redx[2*112+tid] + redx[3*112+tid];
        __syncthreads();

        if (tid < 100){
            const float4* wr = (const float4*)(f1w + (size_t)tid*GHID);
            float s = f1b[tid];
            #pragma unroll 5
            for (int k4 = 0; k4 < 25; ++k4){
                float4 v = wr[k4];
                s += v.x*gs[k4*4] + v.y*gs[k4*4+1] + v.z*gs[k4*4+2] + v.w*gs[k4*4+3];
            }
            fh[tid] = fmaxf(s, 0.f);
        }
        __syncthreads();

        for (int n = tid; n < ANSN; n += 320){
            const float4* wr = (const float4*)(f2w + (size_t)n*GHID);
            float s = f2b[n];
            #pragma unroll 5
            for (int k4 = 0; k4 < 25; ++k4){
                float4 v = wr[k4];
                s += v.x*fh[k4*4] + v.y*fh[k4*4+1] + v.z*fh[k4*4+2] + v.w*fh[k4*4+3];
            }
            lg[n] = fmaxf(s, 0.f);
        }
        __syncthreads();
        float mx = -1e30f;
        for (int n = tid; n < ANSN; n += 320) mx = fmaxf(mx, lg[n]);
        #pragma unroll
        for (int off = 32; off > 0; off >>= 1) mx = fmaxf(mx, __shfl_xor(mx, off));
        if (lane == 0) redm[w] = mx;
        __syncthreads();
        mx = fmaxf(fmaxf(fmaxf(redm[0], redm[1]), fmaxf(redm[2], redm[3])), redm[4]);
        float se = 0.f;
        for (int n = tid; n < ANSN; n += 320) se += expf(lg[n]-mx);
        #pragma unroll
        for (int off = 32; off > 0; off >>= 1) se += __shfl_xor(se, off);
        if (lane == 0) red2[w] = se;
        __syncthreads();
        se = red2[0] + red2[1] + red2[2] + red2[3] + red2[4];
        float lse = logf(se);
        for (int n = tid; n < ANSN; n += 320)
            out[(size_t)b*ANSN + n] = lg[n] - mx - lse;
    }
}

extern "C" void kernel_launch(void* const* d_in, const int* in_sizes, int n_in,
                              void* d_out, int out_size, void* d_ws, size_t ws_size,
                              hipStream_t stream)
{
    const int*   sent  = (const int*)  d_in[0];
    const float* conv  = (const float*)d_in[1];
    const int*   lens  = (const int*)  d_in[2];
    const float* table = (const float*)d_in[3];
    const float* W_ih  = (const float*)d_in[4];
    const float* W_hh  = (const float*)d_in[5];
    const float* b_ih  = (const float*)d_in[6];
    const float* b_hh  = (const float*)d_in[7];
    const float* h0    = (const float*)d_in[8];
    const float* c0    = (const float*)d_in[9];
    const float* g1_w  = (const float*)d_in[10];
    const float* g1_b  = (const float*)d_in[11];
    const float* g2_w  = (const float*)d_in[12];
    const float* g2_b  = (const float*)d_in[13];
    const float* f1_w  = (const float*)d_in[14];
    const float* f1_b  = (const float*)d_in[15];
    const float* f2_w  = (const float*)d_in[16];
    const float* f2_b  = (const float*)d_in[17];
    float* out = (float*)d_out;

    float* ws   = (float*)d_ws;
    int*   slots= (int*)d_ws;                          // 100 slots * 32 ints (64 KB region)
    _Float16* hF = (_Float16*)(ws + 16384);            // 2*4*16*512 f16 = 128 KB
    float* hqB  = ws + 16384 + 32768;                  // 64*512 f32
    float* xgT  = hqB + 64*512;                        // 2000*2048 f32

    // 1. xgT = W_ih @ emb + bias (MFMA f16) — also zeroes barrier slots for kernel 2
    {
        dim3 g(SEQL/TCH, 32);   // x = t-chunk, y = n-tile
        k_xg2<<<g, 256, 0, stream>>>(sent, table, W_ih, b_ih, b_hh, xgT, slots);
    }

    // 2. LSTM + tail, one regular launch (100 blocks, 1/CU -> trivially co-resident)
    k_lstm_tail<<<NBLK, 320, 0, stream>>>(hF, hqB, xgT, W_hh, h0, c0, lens, slots,
                                          conv, g1_w, g1_b, g2_w, g2_b,
                                          f1_w, f1_b, f2_w, f2_b, out);
}

// Round 14
// 323.642 us; speedup vs baseline: 1.6191x; 1.4714x over previous
//
#include <hip/hip_runtime.h>
#include <cmath>

#define BATCH 64
#define SEQL  32
#define EMBD  300
#define HIDD  500
#define NOBJ  64
#define GHID  100
#define ANSN  1000
#define MCOL  2048   // t*64+b column dimension

// partition: 4 batch-groups x 25 unit-blocks
#define GRP    4
#define GBATCH 16
#define BPG    25
#define UPB8   20
#define NBLK   (GRP*BPG)   // 100
#define SLOTP  32          // slot padding in ints (128 B)

#define KPADX  328         // xg LDS row stride in f16 (656 B)
#define TCH    4           // timesteps per xg block

typedef _Float16 half8 __attribute__((ext_vector_type(8)));
typedef float    f32x4 __attribute__((ext_vector_type(4)));

__device__ __forceinline__ float sigmf(float x){ return 1.f/(1.f+expf(-x)); }

// sc1 (coherence-point) primitives: RELAXED agent-scope atomics, no cache-wide fences
__device__ __forceinline__ float2 ld_cc2(const unsigned long long* p){
    union { unsigned long long u; float2 f; } c;
    c.u = __hip_atomic_load(p, __ATOMIC_RELAXED, __HIP_MEMORY_SCOPE_AGENT);
    return c.f;
}
__device__ __forceinline__ void st_cc8(_Float16* p, unsigned long long v){
    __hip_atomic_store((unsigned long long*)p, v, __ATOMIC_RELAXED, __HIP_MEMORY_SCOPE_AGENT);
}

// ---------------- k_xg2: xgT = W_ih @ emb + bias (MFMA f16, r11-proven) + slot zeroing ----------------
__global__ __launch_bounds__(256, 1) void k_xg2(
    const int* __restrict__ sent, const float* __restrict__ table,
    const float* __restrict__ Wih, const float* __restrict__ b_ih,
    const float* __restrict__ b_hh, float* __restrict__ xgT, int* __restrict__ slots)
{
    __shared__ _Float16 Sh[64*KPADX];   // 41984 B, A then B
    __shared__ int sidx[TCH][64];
    int tid = threadIdx.x;
    int tc = blockIdx.x;                // t-chunk (0..7)
    int n0 = blockIdx.y * 64;
    int w = tid >> 6, lane = tid & 63;
    int rA = lane & 15, kb = lane >> 4;

    // zero barrier slots for the following kernel (fresh every launch/replay)
    if (tc == 0 && blockIdx.y == 0 && tid < NBLK)
        __hip_atomic_store(slots + tid*SLOTP, 0, __ATOMIC_RELAXED, __HIP_MEMORY_SCOPE_AGENT);

    for (int i = tid; i < TCH*64; i += 256){
        int tt = i >> 6, b = i & 63;
        sidx[tt][b] = sent[b*SEQL + tc*TCH + tt];
    }
    // stage A: 64 rows x 75 float4 (k=300 exact), f32->f16
    for (int i = tid; i < 64*75; i += 256){
        int n = i / 75, c4 = i - (i/75)*75;
        float4 v = {0.f,0.f,0.f,0.f};
        if (n0 + n < 2000)
            v = *(const float4*)(Wih + (size_t)(n0+n)*300 + c4*4);
        _Float16* dst = &Sh[n*KPADX + c4*4];
        dst[0]=(_Float16)v.x; dst[1]=(_Float16)v.y; dst[2]=(_Float16)v.z; dst[3]=(_Float16)v.w;
    }
    for (int i = tid; i < 64*20; i += 256){   // zero pad k 300..319
        int n = i / 20, k = 300 + (i - (i/20)*20);
        Sh[n*KPADX + k] = (_Float16)0.f;
    }
    __syncthreads();
    // A-fragments -> registers (static indices)
    half8 areg[10];
    #pragma unroll
    for (int ks = 0; ks < 10; ++ks)
        areg[ks] = *(const half8*)&Sh[(w*16 + rA)*KPADX + ks*32 + kb*8];
    float biasr[4];
    #pragma unroll
    for (int r = 0; r < 4; ++r){
        int n = n0 + w*16 + kb*4 + r;
        biasr[r] = (n < 2000) ? b_ih[n] + b_hh[n] : 0.f;
    }
    __syncthreads();   // all A reads done before B overwrites Sh

    for (int tt = 0; tt < TCH; ++tt){
        for (int i = tid; i < 64*75; i += 256){
            int m = i / 75, c4 = i - (i/75)*75;
            float4 v = *(const float4*)(table + (size_t)sidx[tt][m]*300 + c4*4);
            _Float16* dst = &Sh[m*KPADX + c4*4];
            dst[0]=(_Float16)v.x; dst[1]=(_Float16)v.y; dst[2]=(_Float16)v.z; dst[3]=(_Float16)v.w;
        }
        for (int i = tid; i < 64*20; i += 256){
            int m = i / 20, k = 300 + (i - (i/20)*20);
            Sh[m*KPADX + k] = (_Float16)0.f;
        }
        __syncthreads();

        f32x4 acc[4] = {};
        #pragma unroll
        for (int ks = 0; ks < 10; ++ks){
            #pragma unroll
            for (int mc = 0; mc < 4; ++mc){
                half8 bf = *(const half8*)&Sh[(mc*16 + rA)*KPADX + ks*32 + kb*8];
                acc[mc] = __builtin_amdgcn_mfma_f32_16x16x32_f16(areg[ks], bf, acc[mc], 0, 0, 0);
            }
        }
        #pragma unroll
        for (int r = 0; r < 4; ++r){
            int n = n0 + w*16 + kb*4 + r;
            if (n < 2000){
                #pragma unroll
                for (int mc = 0; mc < 4; ++mc)
                    xgT[(size_t)n*MCOL + (tc*TCH+tt)*64 + mc*16 + rA] = acc[mc][r] + biasr[r];
            }
        }
        __syncthreads();
    }
}

// group-local all-to-all barrier (one hop, fence-free; proven r8-r13)
__device__ __forceinline__ void gbarA(int* slots, int grp, int ub, int seq)
{
    __syncthreads();
    if (threadIdx.x == 0)
        __hip_atomic_store(slots + (grp*BPG + ub)*SLOTP, seq,
                           __ATOMIC_RELAXED, __HIP_MEMORY_SCOPE_AGENT);
    if (threadIdx.x < BPG){
        int* s = slots + (grp*BPG + threadIdx.x)*SLOTP;
        while (__hip_atomic_load(s, __ATOMIC_RELAXED, __HIP_MEMORY_SCOPE_AGENT) < seq)
            __builtin_amdgcn_s_sleep(1);
    }
    asm volatile("" ::: "memory");
    __syncthreads();
}

// ---------------- LSTM v8: MFMA f16, batch-grouped, sc1 h exchange (r11 verbatim; regular launch) ----------------
__global__ __launch_bounds__(320, 1) void k_lstm_v8(
    _Float16* __restrict__ hF, float* __restrict__ hqB,
    const float* __restrict__ xgT, const float* __restrict__ Whh,
    const float* __restrict__ h0, const float* __restrict__ c0,
    const int* __restrict__ lens, int* __restrict__ slots)
{
    __shared__ _Float16 Wl[80*512];    // 80 KB
    __shared__ _Float16 hls[16*512];   // 16 KB
    __shared__ float    gl[4*80*16];   // 20 KB
    __shared__ _Float16 hout[16*UPB8]; // 640 B

    int tid = threadIdx.x, bid = blockIdx.x;
    int grp = bid / BPG, ub = bid - grp*BPG;
    int u0  = ub * UPB8;
    int w   = tid >> 6, lane = tid & 63;

    int pb  = tid & 15, puu = tid >> 4;        // puu 0..19
    int pu  = u0 + puu;
    int gb  = grp*GBATCH + pb;                 // global batch row
    float cprev = c0[gb*HIDD + pu];
    float hprev = h0[gb*HIDD + pu];
    int   mylen = lens[gb];
    hout[pb*UPB8 + puu] = (_Float16)hprev;

    for (int i = tid; i < 80*512; i += 320){
        int m = i >> 9, k = i & 511;
        int g = m / UPB8, uu = m - g*UPB8;
        float v = (k < HIDD) ? Whh[(size_t)(g*HIDD + u0 + uu)*HIDD + k] : 0.f;
        int off = (i*2) ^ ((m & 7) << 4);
        *(_Float16*)((char*)Wl + off) = (_Float16)v;
    }
    __syncthreads();
    if (tid < 80){
        int b = tid / 5, q = tid - (tid/5)*5;
        unsigned long long v = *(const unsigned long long*)((const char*)hout + b*40 + q*8);
        st_cc8(hF + ((size_t)(1*GRP + grp)*GBATCH + b)*512 + u0 + q*4, v);
    }
    if (ub == 0 && tid >= 128 && tid < 224){   // zero k-pad 500..511, both buffers
        int j = tid - 128;
        int buf = j / 48, r = j - buf*48;
        int b = r / 3, q = r - (r/3)*3;
        st_cc8(hF + ((size_t)(buf*GRP + grp)*GBATCH + b)*512 + 500 + q*4, 0ULL);
    }
    gbarA(slots, grp, ub, 1);

    const int mA = lane & 15, kb = lane >> 4;

    for (int t = 0; t < SEQL; ++t){
        {
            const char* src = (const char*)(hF + (size_t)(((t&1)^1)*GRP + grp)*GBATCH*512);
            for (int idx = tid; idx < 2048; idx += 320){
                int o = idx*8;
                float2 v = ld_cc2((const unsigned long long*)(src + o));
                *(float2*)((char*)hls + (o ^ (((o >> 10) & 7) << 4))) = v;
            }
        }
        __syncthreads();

        if (w < 4){
            f32x4 acc[5] = {};
            half8 bf[4];
            #pragma unroll
            for (int ks4 = 0; ks4 < 4; ++ks4){
                int kByte = (w*4 + ks4)*64 + kb*16;
                int bOff  = (mA*1024 + kByte) ^ ((mA & 7) << 4);
                bf[ks4] = *(const half8*)((const char*)hls + bOff);
            }
            #pragma unroll
            for (int rt = 0; rt < 5; ++rt){
                #pragma unroll
                for (int ks4 = 0; ks4 < 4; ++ks4){
                    int kByte = (w*4 + ks4)*64 + kb*16;
                    int m = rt*16 + mA;
                    int aOff = (m*1024 + kByte) ^ ((m & 7) << 4);
                    half8 af = *(const half8*)((const char*)Wl + aOff);
                    acc[rt] = __builtin_amdgcn_mfma_f32_16x16x32_f16(af, bf[ks4], acc[rt], 0, 0, 0);
                }
            }
            #pragma unroll
            for (int rt = 0; rt < 5; ++rt)
                #pragma unroll
                for (int r = 0; r < 4; ++r)
                    gl[(w*80 + rt*16 + kb*4 + r)*16 + mA] = acc[rt][r];
        }
        __syncthreads();

        {
            float g4[4];
            #pragma unroll
            for (int g = 0; g < 4; ++g){
                int row = g*UPB8 + puu;
                float s = gl[(0*80 + row)*16 + pb] + gl[(1*80 + row)*16 + pb]
                        + gl[(2*80 + row)*16 + pb] + gl[(3*80 + row)*16 + pb];
                s += xgT[(size_t)(g*HIDD + pu)*MCOL + t*64 + gb];
                g4[g] = s;
            }
            float si = sigmf(g4[0]), sf = sigmf(g4[1]);
            float tg = tanhf(g4[2]), so = sigmf(g4[3]);
            float cn = sf*cprev + si*tg;
            float hn = so*tanhf(cn);
            if (t < mylen){ cprev = cn; hprev = hn; }
            hout[pb*UPB8 + puu] = (_Float16)hprev;
            if (t == SEQL-1) hqB[(size_t)gb*512 + pu] = hprev;   // final h, [b][512] f32
        }
        if (t < SEQL-1){
            __syncthreads();
            if (tid < 80){
                int b = tid / 5, q = tid - (tid/5)*5;
                unsigned long long v = *(const unsigned long long*)((const char*)hout + b*40 + q*8);
                st_cc8(hF + ((size_t)((t&1)*GRP + grp)*GBATCH + b)*512 + u0 + q*4, v);
            }
            gbarA(slots, grp, ub, t + 2);
        }
    }
}

// ---------------- k_tail: qp + ip/jp + pair-MFMA + f1/f2 + log_softmax, one block per b (r11 verbatim) ----------------
__global__ __launch_bounds__(256, 1) void k_tail(
    const float* __restrict__ hqB, const float* __restrict__ conv,
    const float* __restrict__ g1w, const float* __restrict__ g1b,
    const float* __restrict__ g2w, const float* __restrict__ g2b,
    const float* __restrict__ f1w, const float* __restrict__ f1b,
    const float* __restrict__ f2w, const float* __restrict__ f2b,
    float* __restrict__ out)
{
    __shared__ float    convl[24][64];     //  6 KB
    __shared__ float    g1ij[100][48];     // 19.2 KB
    __shared__ float    hb[512];           //  2 KB
    __shared__ float    qpl[112];
    __shared__ float    ipl[NOBJ][104];    // 26.6 KB
    __shared__ float    jpl[NOBJ][132];    // 33.8 KB
    __shared__ float    basel[16][132];    //  8.4 KB
    __shared__ _Float16 g2h[112][136];     // 30.5 KB
    __shared__ float    redx[4][112];
    __shared__ float    gs[112], fh[112];
    __shared__ float    lg[ANSN];          //  4 KB
    __shared__ float    red[4], red2[4];

    int b = blockIdx.x, tid = threadIdx.x;
    int w = tid >> 6, lane = tid & 63;
    int ncol = lane & 15, kb = lane >> 4;

    for (int i = tid; i < 24*64; i += 256)
        convl[i>>6][i&63] = conv[((size_t)b*24 + (i>>6))*64 + (i&63)];
    for (int i = tid; i < 100*48; i += 256){
        int n = i/48, c = i - (i/48)*48;
        g1ij[n][c] = g1w[(size_t)n*548 + 500 + c];
    }
    for (int i = tid; i < 512; i += 256) hb[i] = hqB[(size_t)b*512 + i];
    for (int i = tid; i < 112*136; i += 256){
        int n = i/136, k = i - (i/136)*136;
        g2h[n][k] = (n < 100 && k < 100) ? (_Float16)g2w[n*GHID + k] : (_Float16)0.f;
    }
    __syncthreads();

    if (tid < 100){
        const float4* wr = (const float4*)(g1w + (size_t)tid*548);
        float s = g1b[tid];
        #pragma unroll 5
        for (int k4 = 0; k4 < 125; ++k4){
            float4 v = wr[k4];
            s += v.x*hb[k4*4] + v.y*hb[k4*4+1] + v.z*hb[k4*4+2] + v.w*hb[k4*4+3];
        }
        qpl[tid] = s;
    }
    for (int i = tid; i < NOBJ*100; i += 256){
        int o = i / 100, n = i - (i/100)*100;
        float sj = 0.f, si = 0.f;
        #pragma unroll
        for (int c = 0; c < 24; ++c){
            float v = convl[c][o];
            sj += v * g1ij[n][c];
            si += v * g1ij[n][24+c];
        }
        ipl[o][n] = si;
        jpl[o][n] = sj;
    }
    for (int i = tid; i < NOBJ*32; i += 256) jpl[i>>5][100 + (i&31)] = 0.f;

    float gb7[7];
    #pragma unroll
    for (int nt = 0; nt < 7; ++nt){
        int n = nt*16 + ncol;
        gb7[nt] = (n < 100) ? g2b[n] : 0.f;
    }

    f32x4 sacc[7] = {};
    for (int ic = 0; ic < 4; ++ic){
        __syncthreads();
        for (int i = tid; i < 16*132; i += 256){
            int il = i / 132, k = i - (i/132)*132;
            basel[il][k] = (k < 100) ? qpl[k] + ipl[ic*16 + il][k] : 0.f;
        }
        __syncthreads();
        #pragma unroll
        for (int it = 0; it < 4; ++it){
            int il = w*4 + it;
            #pragma unroll
            for (int jc = 0; jc < 4; ++jc){
                f32x4 acc[7] = {};
                int jrow = jc*16 + ncol;
                #pragma unroll
                for (int ks = 0; ks < 4; ++ks){
                    int k0 = ks*32 + kb*8;
                    const float* jpp = &jpl[jrow][k0];
                    const float* bpp = &basel[il][k0];
                    half8 af;
                    #pragma unroll
                    for (int e = 0; e < 8; ++e)
                        af[e] = (_Float16)fmaxf(jpp[e] + bpp[e], 0.f);
                    #pragma unroll
                    for (int nt = 0; nt < 7; ++nt){
                        half8 bf = *(const half8*)&g2h[nt*16 + ncol][k0];
                        acc[nt] = __builtin_amdgcn_mfma_f32_16x16x32_f16(af, bf, acc[nt], 0, 0, 0);
                    }
                }
                #pragma unroll
                for (int nt = 0; nt < 7; ++nt)
                    #pragma unroll
                    for (int r = 0; r < 4; ++r)
                        sacc[nt][r] += fmaxf(acc[nt][r] + gb7[nt], 0.f);
            }
        }
    }
    #pragma unroll
    for (int nt = 0; nt < 7; ++nt){
        float s = sacc[nt][0] + sacc[nt][1] + sacc[nt][2] + sacc[nt][3];
        s += __shfl_xor(s, 16);
        s += __shfl_xor(s, 32);
        if (lane < 16) redx[w][nt*16 + lane] = s;
    }
    __syncthreads();
    if (tid < 100) gs[tid] = redx[0][tid] + redx[1][tid] + redx[2][tid] + redx[3][tid];
    __syncthreads();

    if (tid < 100){
        const float4* wr = (const float4*)(f1w + (size_t)tid*GHID);
        float s = f1b[tid];
        #pragma unroll 5
        for (int k4 = 0; k4 < 25; ++k4){
            float4 v = wr[k4];
            s += v.x*gs[k4*4] + v.y*gs[k4*4+1] + v.z*gs[k4*4+2] + v.w*gs[k4*4+3];
        }
        fh[tid] = fmaxf(s, 0.f);
    }
    __syncthreads();

    for (int n = tid; n < ANSN; n += 256){
        const float4* wr = (const float4*)(f2w + (size_t)n*GHID);
        float s = f2b[n];
        #pragma unroll 5
        for (int k4 = 0; k4 < 25; ++k4){
            float4 v = wr[k4];
            s += v.x*fh[k4*4] + v.y*fh[k4*4+1] + v.z*fh[k4*4+2] + v.w*fh[k4*4+3];
        }
        lg[n] = fmaxf(s, 0.f);
    }
    __syncthreads();
    float mx = -1e30f;
    for (int n = tid; n < ANSN; n += 256) mx = fmaxf(mx, lg[n]);
    #pragma unroll
    for (int off = 32; off > 0; off >>= 1) mx = fmaxf(mx, __shfl_xor(mx, off));
    if ((tid & 63) == 0) red[tid >> 6] = mx;
    __syncthreads();
    mx = fmaxf(fmaxf(red[0], red[1]), fmaxf(red[2], red[3]));
    float se = 0.f;
    for (int n = tid; n < ANSN; n += 256) se += expf(lg[n]-mx);
    #pragma unroll
    for (int off = 32; off > 0; off >>= 1) se += __shfl_xor(se, off);
    if ((tid & 63) == 0) red2[tid >> 6] = se;
    __syncthreads();
    se = red2[0]+red2[1]+red2[2]+red2[3];
    float lse = logf(se);
    for (int n = tid; n < ANSN; n += 256) out[(size_t)b*ANSN + n] = lg[n] - mx - lse;
}

extern "C" void kernel_launch(void* const* d_in, const int* in_sizes, int n_in,
                              void* d_out, int out_size, void* d_ws, size_t ws_size,
                              hipStream_t stream)
{
    const int*   sent  = (const int*)  d_in[0];
    const float* conv  = (const float*)d_in[1];
    const int*   lens  = (const int*)  d_in[2];
    const float* table = (const float*)d_in[3];
    const float* W_ih  = (const float*)d_in[4];
    const float* W_hh  = (const float*)d_in[5];
    const float* b_ih  = (const float*)d_in[6];
    const float* b_hh  = (const float*)d_in[7];
    const float* h0    = (const float*)d_in[8];
    const float* c0    = (const float*)d_in[9];
    const float* g1_w  = (const float*)d_in[10];
    const float* g1_b  = (const float*)d_in[11];
    const float* g2_w  = (const float*)d_in[12];
    const float* g2_b  = (const float*)d_in[13];
    const float* f1_w  = (const float*)d_in[14];
    const float* f1_b  = (const float*)d_in[15];
    const float* f2_w  = (const float*)d_in[16];
    const float* f2_b  = (const float*)d_in[17];
    float* out = (float*)d_out;

    float* ws   = (float*)d_ws;
    int*   slots= (int*)d_ws;                          // 100 slots * 32 ints (64 KB region)
    _Float16* hF = (_Float16*)(ws + 16384);            // 2*4*16*512 f16 = 128 KB
    float* hqB  = ws + 16384 + 32768;                  // 64*512 f32
    float* xgT  = hqB + 64*512;                        // 2000*2048 f32

    // 1. xgT = W_ih @ emb + bias (MFMA f16) — also zeroes barrier slots for kernel 2
    {
        dim3 g(SEQL/TCH, 32);   // x = t-chunk, y = n-tile
        k_xg2<<<g, 256, 0, stream>>>(sent, table, W_ih, b_ih, b_hh, xgT, slots);
    }

    // 2. MFMA LSTM, regular launch (100 blocks, 1/CU -> trivially co-resident)
    k_lstm_v8<<<NBLK, 320, 0, stream>>>(hF, hqB, xgT, W_hh, h0, c0, lens, slots);

    // 3. fused tail: qp/ipjp + pair MFMA + f1/f2 + log_softmax
    k_tail<<<BATCH, 256, 0, stream>>>(hqB, conv, g1_w, g1_b, g2_w, g2_b,
                                      f1_w, f1_b, f2_w, f2_b, out);
}